// Round 10
// baseline (176.841 us; speedup 1.0000x reference)
//
#include <hip/hip_runtime.h>
#include <cmath>

#define B_ 2
#define S_ 2048
#define E_ 1024
#define H_ 16
#define D_ 64

typedef __attribute__((ext_vector_type(8)))  short  bf16x8;
typedef __attribute__((ext_vector_type(4)))  float  f32x4;
typedef __attribute__((ext_vector_type(16))) float  f32x16;
typedef __attribute__((ext_vector_type(8)))  unsigned short ushort8;
typedef __attribute__((ext_vector_type(4)))  unsigned short ushort4v;
typedef __attribute__((ext_vector_type(4)))  unsigned int   u32x4;
typedef unsigned int u32;

__device__ __forceinline__ ushort f2bf(float f) {
    u32 u = __float_as_uint(f);
    u32 r = (u + 0x7fffu + ((u >> 16) & 1u)) >> 16;
    return (ushort)r;
}
__device__ __forceinline__ void gload_lds16(const ushort* gp, ushort* lp) {
    auto g = (const __attribute__((address_space(1))) u32*)gp;
    auto l = (__attribute__((address_space(3))) u32*)lp;
    __builtin_amdgcn_global_load_lds(g, l, 16, 0, 0);
}
__device__ __forceinline__ u32 cvtpk_bf16(float lo, float hi) {
    u32 r;
    asm("v_cvt_pk_bf16_f32 %0, %1, %2" : "=v"(r) : "v"(lo), "v"(hi));
    return r;
}
// raw v_exp_f32 (2^x); input always <= 0 here, hw handles -inf -> 0
__device__ __forceinline__ float hw_exp2(float x) {
    float r;
    asm("v_exp_f32 %0, %1" : "=v"(r) : "v"(x));
    return r;
}
// hardware sin/cos of (2*pi*rev); v_fract first keeps input in-domain
__device__ __forceinline__ void hw_sincos_rev(float rev, float* sn, float* cs) {
    float fr;
    asm("v_fract_f32 %0, %1" : "=v"(fr) : "v"(rev));
    asm("v_sin_f32 %0, %1" : "=v"(*sn) : "v"(fr));
    asm("v_cos_f32 %0, %1" : "=v"(*cs) : "v"(fr));
}

// ---------------------------------------------------------------------------
// cast x (f32 -> bf16), 8 elems/thread
// ---------------------------------------------------------------------------
__global__ __launch_bounds__(256) void cast_x(const float* __restrict__ in,
                                              ushort* __restrict__ out) {
    const int idx = blockIdx.x * 256 + threadIdx.x;
    const float4 a = *reinterpret_cast<const float4*>(&in[(size_t)idx * 8]);
    const float4 b = *reinterpret_cast<const float4*>(&in[(size_t)idx * 8 + 4]);
    ushort8 o;
    o[0] = f2bf(a.x); o[1] = f2bf(a.y); o[2] = f2bf(a.z); o[3] = f2bf(a.w);
    o[4] = f2bf(b.x); o[5] = f2bf(b.y); o[6] = f2bf(b.z); o[7] = f2bf(b.w);
    *reinterpret_cast<ushort8*>(&out[(size_t)idx * 8]) = o;
}

// ---------------------------------------------------------------------------
// cast + transpose weights: W[k][n] f32 -> Wt[n][k] bf16  (1024x1024 each)
// ---------------------------------------------------------------------------
__global__ __launch_bounds__(256) void castT_w(
    const float* __restrict__ Wq, const float* __restrict__ Wk,
    const float* __restrict__ Wv, const float* __restrict__ Wo,
    ushort* __restrict__ WtQKV, ushort* __restrict__ WtO)
{
    __shared__ float tile[32][33];
    const float* src; ushort* dst;
    switch (blockIdx.z) {
        case 0:  src = Wq; dst = WtQKV;                 break;
        case 1:  src = Wk; dst = WtQKV + 1024 * 1024;   break;
        case 2:  src = Wv; dst = WtQKV + 2048 * 1024;   break;
        default: src = Wo; dst = WtO;                   break;
    }
    const int k0 = blockIdx.y * 32, n0 = blockIdx.x * 32;
    const int tx = threadIdx.x & 31, ty = threadIdx.x >> 5;
    #pragma unroll
    for (int i = 0; i < 4; ++i)
        tile[i * 8 + ty][tx] = src[(size_t)(k0 + i * 8 + ty) * 1024 + n0 + tx];
    __syncthreads();
    #pragma unroll
    for (int i = 0; i < 4; ++i)
        dst[(size_t)(n0 + i * 8 + ty) * 1024 + k0 + tx] = f2bf(tile[tx][i * 8 + ty]);
}

// ---------------------------------------------------------------------------
// QKV GEMM (M=4096, N=3072, K=1024), 128x128 tile, BK=64, T2-swizzled LDS.
// Epilogue fuses bias + RoPE (HW v_sin/v_cos on revolutions); Q scaled by
// 0.125*log2(e).  Writes Q->Qb, K->Kb (row-major), V->Vt (transposed).
// ---------------------------------------------------------------------------
__global__ __launch_bounds__(256, 3) void gemm_qkv(
    const ushort* __restrict__ A, const ushort* __restrict__ Bt,
    const float* __restrict__ bq, const float* __restrict__ bk,
    const float* __restrict__ bv,
    ushort* __restrict__ Qb, ushort* __restrict__ Kb, ushort* __restrict__ Vt)
{
    __shared__ ushort As[128 * 64];
    __shared__ ushort Bs[128 * 64];
    const int t = threadIdx.x, w = t >> 6, l = t & 63;
    const int lr = l & 15, lg = l >> 4;
    const int wr = w >> 1, wc = w & 1;
    const int row0 = blockIdx.y * 128, col0 = blockIdx.x * 128;

    f32x4 acc[4][4] = {};

    for (int k0 = 0; k0 < 1024; k0 += 64) {
        #pragma unroll
        for (int i = 0; i < 4; ++i) {
            const int r  = w * 32 + i * 8 + (l >> 3);
            const int cs = ((l & 7) ^ (r & 7)) * 8;          // src pre-swizzle
            gload_lds16(&A [(size_t)(row0 + r) * 1024 + k0 + cs], &As[(w * 32 + i * 8) * 64]);
            gload_lds16(&Bt[(size_t)(col0 + r) * 1024 + k0 + cs], &Bs[(w * 32 + i * 8) * 64]);
        }
        asm volatile("s_waitcnt vmcnt(0)");
        __syncthreads();

        #pragma unroll
        for (int kk = 0; kk < 2; ++kk) {
            bf16x8 af[4], bfr[4];
            #pragma unroll
            for (int m = 0; m < 4; ++m)
                af[m] = *reinterpret_cast<const bf16x8*>(
                    &As[(wr * 64 + m * 16 + lr) * 64 + (((kk * 4 + lg) ^ (lr & 7)) * 8)]);
            #pragma unroll
            for (int n = 0; n < 4; ++n)
                bfr[n] = *reinterpret_cast<const bf16x8*>(
                    &Bs[(wc * 64 + n * 16 + lr) * 64 + (((kk * 4 + lg) ^ (lr & 7)) * 8)]);
            #pragma unroll
            for (int m = 0; m < 4; ++m)
                #pragma unroll
                for (int n = 0; n < 4; ++n)
                    acc[m][n] = __builtin_amdgcn_mfma_f32_16x16x32_bf16(
                        af[m], bfr[n], acc[m][n], 0, 0, 0);
        }
        __syncthreads();
    }

    const int cbase = col0 + wc * 64;          // wave's 64-col span (one head)
    const int cls   = cbase >> 10;             // 0=Q, 1=K, 2=V
    const int hcol  = cbase & 1023;            // head-aligned col within 1024
    const float* bias = (cls == 0) ? bq : (cls == 1 ? bk : bv);

    if (cls < 2) {
        ushort* dst = (cls == 0) ? Qb : Kb;
        const float qscale = (cls == 0) ? 0.1803368801f : 1.0f;  // 0.125*log2(e)
        #pragma unroll
        for (int m = 0; m < 4; ++m) {
            const int rbase = row0 + wr * 64 + m * 16 + lg * 4;
            #pragma unroll
            for (int n = 0; n < 2; ++n) {
                const int i    = n * 16 + lr;                  // 0..31
                const float b0 = bias[hcol + i];
                const float b1 = bias[hcol + i + 32];
                // invf / (2*pi): angle in revolutions = s * invf_rev
                const float invf_rev =
                    exp2f(-(float)i * 0.415241012f) * 0.15915494309f;
                #pragma unroll
                for (int r = 0; r < 4; ++r) {
                    const int row = rbase + r;
                    const int s   = row & (S_ - 1);
                    float sn, cs_;
                    hw_sincos_rev((float)s * invf_rev, &sn, &cs_);
                    const float v0 = acc[m][n][r]     + b0;
                    const float v1 = acc[m][n + 2][r] + b1;
                    dst[(size_t)row * 1024 + hcol + i]      = f2bf((v0 * cs_ - v1 * sn) * qscale);
                    dst[(size_t)row * 1024 + hcol + i + 32] = f2bf((v1 * cs_ + v0 * sn) * qscale);
                }
            }
        }
    } else {
        const int h = hcol >> 6;
        #pragma unroll
        for (int m = 0; m < 4; ++m) {
            const int rbase = row0 + wr * 64 + m * 16 + lg * 4;
            const int bb = rbase >> 11, s0 = rbase & (S_ - 1);
            #pragma unroll
            for (int n = 0; n < 4; ++n) {
                const int d = n * 16 + lr;
                const float bia = bias[hcol + d];
                ushort4v pk;
                #pragma unroll
                for (int r = 0; r < 4; ++r) pk[r] = f2bf(acc[m][n][r] + bia);
                *reinterpret_cast<ushort4v*>(
                    &Vt[((size_t)(bb * 16 + h) * 64 + d) * S_ + s0]) = pk;
            }
        }
    }
}

// ---------------------------------------------------------------------------
// Output GEMM: C[M,1024] f32 = A @ Wt^T + bias
// ---------------------------------------------------------------------------
__global__ __launch_bounds__(256, 1) void gemm_out(
    const ushort* __restrict__ A, const ushort* __restrict__ Bt,
    const float* __restrict__ bias, float* __restrict__ C, int N, int K)
{
    __shared__ ushort As[128 * 64];
    __shared__ ushort Bs[128 * 64];
    const int t = threadIdx.x, w = t >> 6, l = t & 63;
    const int lr = l & 15, lg = l >> 4;
    const int wr = w >> 1, wc = w & 1;
    const int row0 = blockIdx.y * 128, col0 = blockIdx.x * 128;

    f32x4 acc[4][4] = {};

    for (int k0 = 0; k0 < K; k0 += 64) {
        #pragma unroll
        for (int i = 0; i < 4; ++i) {
            const int r  = w * 32 + i * 8 + (l >> 3);
            const int cs = ((l & 7) ^ (r & 7)) * 8;
            gload_lds16(&A [(size_t)(row0 + r) * K + k0 + cs], &As[(w * 32 + i * 8) * 64]);
            gload_lds16(&Bt[(size_t)(col0 + r) * K + k0 + cs], &Bs[(w * 32 + i * 8) * 64]);
        }
        asm volatile("s_waitcnt vmcnt(0)");
        __syncthreads();

        #pragma unroll
        for (int kk = 0; kk < 2; ++kk) {
            bf16x8 af[4], bfr[4];
            #pragma unroll
            for (int m = 0; m < 4; ++m)
                af[m] = *reinterpret_cast<const bf16x8*>(
                    &As[(wr * 64 + m * 16 + lr) * 64 + (((kk * 4 + lg) ^ (lr & 7)) * 8)]);
            #pragma unroll
            for (int n = 0; n < 4; ++n)
                bfr[n] = *reinterpret_cast<const bf16x8*>(
                    &Bs[(wc * 64 + n * 16 + lr) * 64 + (((kk * 4 + lg) ^ (lr & 7)) * 8)]);
            #pragma unroll
            for (int m = 0; m < 4; ++m)
                #pragma unroll
                for (int n = 0; n < 4; ++n)
                    acc[m][n] = __builtin_amdgcn_mfma_f32_16x16x32_bf16(
                        af[m], bfr[n], acc[m][n], 0, 0, 0);
        }
        __syncthreads();
    }

    #pragma unroll
    for (int m = 0; m < 4; ++m) {
        const int rbase = row0 + wr * 64 + m * 16 + lg * 4;
        #pragma unroll
        for (int n = 0; n < 4; ++n) {
            const int c = col0 + wc * 64 + n * 16 + lr;
            const float bv = bias[c];
            #pragma unroll
            for (int r = 0; r < 4; ++r)
                C[(size_t)(rbase + r) * N + c] = acc[m][n][r] + bv;
        }
    }
}

// ---------------------------------------------------------------------------
// attn8: 2-tile software pipeline (att[2] / T15).  Per iteration:
//   QK(t+1) [MFMA, independent] || softmax(t) [VALU] -> PV(t) [MFMA]
//   -> V-read(t+1) -> vmcnt(0)+lgkmcnt(0) -> s_barrier.
// V fragments carried in registers so STAGE(t+2) reuses the buffer with a
// full-iteration prefetch span.  sacc/vf ping-pong via statically named
// sA/sB, vA/vB (no runtime-indexed register arrays).  Swizzled LDS read
// offsets are loop-invariant (4 ints serve all 24 reads).
// ---------------------------------------------------------------------------
__global__ __launch_bounds__(128, 2) void attn8(
    const ushort* __restrict__ Qb, const ushort* __restrict__ Kb,
    const ushort* __restrict__ Vt, ushort* __restrict__ AO)
{
    __shared__ ushort Ks[2][64 * 64];
    __shared__ ushort Vs[2][64 * 64];

    const int tid = threadIdx.x, w = tid >> 6, l = tid & 63;
    const int lq = l & 31, hi = l >> 5;
    const int idx = blockIdx.x;
    const int bh = idx & 31, b = bh >> 4, h = bh & 15;
    const int qt = 31 - (idx >> 5);            // longest q-tiles dispatch first
    const int q0 = qt * 64, qw = q0 + w * 32;
    const int qg = qw + lq;                    // this lane's q row
    const int nt = qt + 1;                     // number of 64-key tiles

    const ushort* Kbh = Kb + (size_t)b * S_ * 1024 + h * 64;
    const ushort* Vbh = Vt + (size_t)bh * 64 * S_;

    // Q fragments (B-operand): qf[dc] = Q[qg][16*dc + 8*hi + j]
    bf16x8 qf[4];
    {
        const ushort* qrow = Qb + (size_t)(b * S_ + qg) * 1024 + h * 64 + 8 * hi;
        #pragma unroll
        for (int dc = 0; dc < 4; ++dc)
            qf[dc] = *reinterpret_cast<const bf16x8*>(qrow + 16 * dc);
    }

    // loop-invariant swizzled LDS element offsets (serve K and V reads):
    // K(sub,dc)   -> off[dc]       + sub*2048
    // V(dt,sub,kc)-> off[2*sub+kc] + dt*2048
    int off[4];
    #pragma unroll
    for (int j = 0; j < 4; ++j)
        off[j] = lq * 64 + (((2 * j + hi) ^ (lq & 7)) * 8);

    f32x16 oacc[2] = {};                       // O^T: rows=d, col=q(lane)
    float mrow = -3.0e38f, lrow = 0.f;

    auto STAGE = [&](int buf, int kt) {
        #pragma unroll
        for (int i = 0; i < 4; ++i) {
            const int cid = i * 128 + tid;                   // 0..511
            const int r   = cid >> 3;                        // 0..63
            const int cs  = ((cid & 7) ^ (r & 7)) * 8;       // src pre-swizzle
            const int db  = (i * 128 + w * 64) * 8;          // wave-uniform dest
            gload_lds16(&Kbh[(size_t)(kt + r) * 1024 + cs], &Ks[buf][db]);
            gload_lds16(&Vbh[(size_t)r * S_ + kt + cs],     &Vs[buf][db]);
        }
    };

    auto QK = [&](f32x16 (&sn)[2], const ushort* Kc) {
        __builtin_amdgcn_s_setprio(1);
        #pragma unroll
        for (int sub = 0; sub < 2; ++sub) {
            sn[sub] = f32x16{0.f};
            #pragma unroll
            for (int dc = 0; dc < 4; ++dc) {
                const bf16x8 kf = *reinterpret_cast<const bf16x8*>(
                    &Kc[off[dc] + sub * 2048]);
                sn[sub] = __builtin_amdgcn_mfma_f32_32x32x16_bf16(
                    kf, qf[dc], sn[sub], 0, 0, 0);
            }
        }
        __builtin_amdgcn_s_setprio(0);
    };

    auto VREAD = [&](bf16x8 (&vn)[2][4], const ushort* Vc) {
        #pragma unroll
        for (int dt = 0; dt < 2; ++dt)
            #pragma unroll
            for (int j = 0; j < 4; ++j)
                vn[dt][j] = *reinterpret_cast<const bf16x8*>(
                    &Vc[off[j] + dt * 2048]);
    };

    auto SMPV = [&](f32x16 (&sc)[2], bf16x8 (&vc)[2][4], int kt, bool domask) {
        if (domask) {
            #pragma unroll
            for (int sub = 0; sub < 2; ++sub)
                if (kt + sub * 32 + 31 > qw) {
                    #pragma unroll
                    for (int r = 0; r < 16; ++r) {
                        const int kg = kt + sub * 32 + (r & 3) + 8 * (r >> 2) + 4 * hi;
                        if (kg > qg) sc[sub][r] = -1.0e30f;
                    }
                }
        }
        // row max: tree (depth 5) + one cross-half exchange
        float mx[16];
        #pragma unroll
        for (int r = 0; r < 16; ++r) mx[r] = fmaxf(sc[0][r], sc[1][r]);
        #pragma unroll
        for (int s2 = 8; s2 > 0; s2 >>= 1)
            #pragma unroll
            for (int r = 0; r < s2; ++r) mx[r] = fmaxf(mx[r], mx[r + s2]);
        const float tm = fmaxf(mx[0], __shfl_xor(mx[0], 32));

        // rescale (exact skip when no lane has a new max)
        if (!__all(tm <= mrow)) {
            const float mnew = fmaxf(mrow, tm);
            const float corr = hw_exp2(mrow - mnew);
            lrow *= corr;
            #pragma unroll
            for (int r = 0; r < 16; ++r) { oacc[0][r] *= corr; oacc[1][r] *= corr; }
            mrow = mnew;
        }

        // p = exp2(s - m); tree row-sum
        float sm[16];
        #pragma unroll
        for (int sub = 0; sub < 2; ++sub)
            #pragma unroll
            for (int r = 0; r < 16; ++r)
                sc[sub][r] = hw_exp2(sc[sub][r] - mrow);
        #pragma unroll
        for (int r = 0; r < 16; ++r) sm[r] = sc[0][r] + sc[1][r];
        #pragma unroll
        for (int s2 = 8; s2 > 0; s2 >>= 1)
            #pragma unroll
            for (int r = 0; r < s2; ++r) sm[r] += sm[r + s2];
        lrow += sm[0] + __shfl_xor(sm[0], 32);

        // pack P (cvt_pk + permlane32_swap) and O^T += V^T @ P^T
        #pragma unroll
        for (int sub = 0; sub < 2; ++sub) {
            u32 wpk[8];
            #pragma unroll
            for (int i = 0; i < 8; ++i)
                wpk[i] = cvtpk_bf16(sc[sub][2 * i], sc[sub][2 * i + 1]);
            u32 a0 = wpk[0], b0 = wpk[2];
            u32 a1 = wpk[1], b1 = wpk[3];
            u32 a2 = wpk[4], b2 = wpk[6];
            u32 a3 = wpk[5], b3 = wpk[7];
            asm("v_permlane32_swap_b32 %0, %1" : "+v"(a0), "+v"(b0));
            asm("v_permlane32_swap_b32 %0, %1" : "+v"(a1), "+v"(b1));
            asm("v_permlane32_swap_b32 %0, %1" : "+v"(a2), "+v"(b2));
            asm("v_permlane32_swap_b32 %0, %1" : "+v"(a3), "+v"(b3));
            u32x4 pw0, pw1;
            pw0[0] = a0; pw0[1] = a1; pw0[2] = b0; pw0[3] = b1;
            pw1[0] = a2; pw1[1] = a3; pw1[2] = b2; pw1[3] = b3;
            const bf16x8 pb0 = __builtin_bit_cast(bf16x8, pw0);
            const bf16x8 pb1 = __builtin_bit_cast(bf16x8, pw1);
            __builtin_amdgcn_s_setprio(1);
            #pragma unroll
            for (int dt = 0; dt < 2; ++dt)
                oacc[dt] = __builtin_amdgcn_mfma_f32_32x32x16_bf16(
                    vc[dt][2 * sub], pb0, oacc[dt], 0, 0, 0);
            #pragma unroll
            for (int dt = 0; dt < 2; ++dt)
                oacc[dt] = __builtin_amdgcn_mfma_f32_32x32x16_bf16(
                    vc[dt][2 * sub + 1], pb1, oacc[dt], 0, 0, 0);
            __builtin_amdgcn_s_setprio(0);
        }
    };

    // ---- preamble: stage tiles 0 (and 1), QK(0), V(0) ----
    STAGE(0, 0);
    if (nt > 1) {
        STAGE(1, 64);
        asm volatile("s_waitcnt vmcnt(8)" ::: "memory");   // tile0's 8 done
    } else {
        asm volatile("s_waitcnt vmcnt(0)" ::: "memory");
    }
    __builtin_amdgcn_s_barrier();

    f32x16 sA[2], sB[2];
    bf16x8 vA[2][4], vB[2][4];
    QK(sA, &Ks[0][0]);
    VREAD(vA, &Vs[0][0]);
    asm volatile("s_waitcnt vmcnt(0) lgkmcnt(0)" ::: "memory");  // tile1 staged; buf0 reads landed
    __builtin_amdgcn_s_barrier();

#define PIPE_ITER(SC, SN, VC, VN, T, BUFN, BUFC)                        \
    {                                                                    \
        QK(SN, &Ks[BUFN][0]);                /* QK(t+1), indep MFMA */   \
        if ((T) + 2 < nt) STAGE(BUFC, ((T) + 2) * 64);                   \
        SMPV(SC, VC, (T) * 64, false);       /* softmax+PV(t), VALU */   \
        VREAD(VN, &Vs[BUFN][0]);             /* V(t+1) -> regs */        \
        asm volatile("s_waitcnt vmcnt(0) lgkmcnt(0)" ::: "memory");      \
        __builtin_amdgcn_s_barrier();                                    \
    }

    for (int t = 0; t + 1 < nt; ++t) {
        if ((t & 1) == 0) PIPE_ITER(sA, sB, vA, vB, t, 1, 0)
        else              PIPE_ITER(sB, sA, vB, vA, t, 0, 1)
    }
#undef PIPE_ITER

    // ---- tail: softmax+PV on last tile (only place masking happens) ----
    if (((nt - 1) & 1) == 0) SMPV(sA, vA, (nt - 1) * 64, true);
    else                     SMPV(sB, vB, (nt - 1) * 64, true);

    // ---- epilogue: O^T / l -> AO[q][d] (lane's own q row) ----
    const float inv = 1.f / lrow;
    ushort* aorow = AO + (size_t)(b * S_ + qg) * 1024 + h * 64;
    #pragma unroll
    for (int dt = 0; dt < 2; ++dt)
        #pragma unroll
        for (int g = 0; g < 4; ++g) {
            const int d0 = dt * 32 + g * 8 + hi * 4;
            ushort4v pk;
            #pragma unroll
            for (int j = 0; j < 4; ++j) pk[j] = f2bf(oacc[dt][g * 4 + j] * inv);
            *reinterpret_cast<ushort4v*>(&aorow[d0]) = pk;
        }
}

// ---------------------------------------------------------------------------
extern "C" void kernel_launch(void* const* d_in, const int* in_sizes, int n_in,
                              void* d_out, int out_size, void* d_ws, size_t ws_size,
                              hipStream_t stream)
{
    const float* x  = (const float*)d_in[0];
    const float* Wq = (const float*)d_in[2];
    const float* bq = (const float*)d_in[3];
    const float* Wk = (const float*)d_in[4];
    const float* bk = (const float*)d_in[5];
    const float* Wv = (const float*)d_in[6];
    const float* bv = (const float*)d_in[7];
    const float* Wo = (const float*)d_in[8];
    const float* bo = (const float*)d_in[9];
    float* out = (float*)d_out;

    const size_t tok = (size_t)B_ * S_;            // 4096
    ushort* xb    = (ushort*)d_ws;                 // 4M elems
    ushort* WtQKV = xb + tok * E_;                 // 3M
    ushort* WtO   = WtQKV + (size_t)3072 * 1024;   // 1M
    ushort* Qb    = WtO + (size_t)1024 * 1024;     // 4M
    ushort* Kb    = Qb + tok * E_;                 // 4M
    ushort* Vt    = Kb + tok * E_;                 // 4M
    ushort* AO    = Vt + tok * E_;                 // 4M

    cast_x<<<2048, 256, 0, stream>>>(x, xb);
    castT_w<<<dim3(32, 32, 4), 256, 0, stream>>>(Wq, Wk, Wv, Wo, WtQKV, WtO);

    gemm_qkv<<<dim3(24, 32), 256, 0, stream>>>(xb, WtQKV, bq, bk, bv, Qb, Kb, Vt);

    attn8<<<1024, 128, 0, stream>>>(Qb, Kb, Vt, AO);

    gemm_out<<<dim3(8, 32), 256, 0, stream>>>(AO, WtO, bo, out, 1024, 1024);
}

// Round 11
// 132.186 us; speedup vs baseline: 1.3378x; 1.3378x over previous
//
#include <hip/hip_runtime.h>
#include <cmath>

#define B_ 2
#define S_ 2048
#define E_ 1024
#define H_ 16
#define D_ 64

typedef __attribute__((ext_vector_type(8)))  short  bf16x8;
typedef __attribute__((ext_vector_type(4)))  float  f32x4;
typedef __attribute__((ext_vector_type(16))) float  f32x16;
typedef __attribute__((ext_vector_type(8)))  unsigned short ushort8;
typedef __attribute__((ext_vector_type(4)))  unsigned short ushort4v;
typedef __attribute__((ext_vector_type(4)))  unsigned int   u32x4;
typedef unsigned int u32;

__device__ __forceinline__ ushort f2bf(float f) {
    u32 u = __float_as_uint(f);
    u32 r = (u + 0x7fffu + ((u >> 16) & 1u)) >> 16;
    return (ushort)r;
}
__device__ __forceinline__ void gload_lds16(const ushort* gp, ushort* lp) {
    auto g = (const __attribute__((address_space(1))) u32*)gp;
    auto l = (__attribute__((address_space(3))) u32*)lp;
    __builtin_amdgcn_global_load_lds(g, l, 16, 0, 0);
}
__device__ __forceinline__ u32 cvtpk_bf16(float lo, float hi) {
    u32 r;
    asm("v_cvt_pk_bf16_f32 %0, %1, %2" : "=v"(r) : "v"(lo), "v"(hi));
    return r;
}
// raw v_exp_f32 (2^x); input always <= 0 here, hw handles -inf -> 0
__device__ __forceinline__ float hw_exp2(float x) {
    float r;
    asm("v_exp_f32 %0, %1" : "=v"(r) : "v"(x));
    return r;
}
// hardware sin/cos of (2*pi*rev); v_fract first keeps input in-domain
__device__ __forceinline__ void hw_sincos_rev(float rev, float* sn, float* cs) {
    float fr;
    asm("v_fract_f32 %0, %1" : "=v"(fr) : "v"(rev));
    asm("v_sin_f32 %0, %1" : "=v"(*sn) : "v"(fr));
    asm("v_cos_f32 %0, %1" : "=v"(*cs) : "v"(fr));
}

// ---------------------------------------------------------------------------
// cast x (f32 -> bf16), 8 elems/thread
// ---------------------------------------------------------------------------
__global__ __launch_bounds__(256) void cast_x(const float* __restrict__ in,
                                              ushort* __restrict__ out) {
    const int idx = blockIdx.x * 256 + threadIdx.x;
    const float4 a = *reinterpret_cast<const float4*>(&in[(size_t)idx * 8]);
    const float4 b = *reinterpret_cast<const float4*>(&in[(size_t)idx * 8 + 4]);
    ushort8 o;
    o[0] = f2bf(a.x); o[1] = f2bf(a.y); o[2] = f2bf(a.z); o[3] = f2bf(a.w);
    o[4] = f2bf(b.x); o[5] = f2bf(b.y); o[6] = f2bf(b.z); o[7] = f2bf(b.w);
    *reinterpret_cast<ushort8*>(&out[(size_t)idx * 8]) = o;
}

// ---------------------------------------------------------------------------
// cast + transpose weights: W[k][n] f32 -> Wt[n][k] bf16  (1024x1024 each)
// ---------------------------------------------------------------------------
__global__ __launch_bounds__(256) void castT_w(
    const float* __restrict__ Wq, const float* __restrict__ Wk,
    const float* __restrict__ Wv, const float* __restrict__ Wo,
    ushort* __restrict__ WtQKV, ushort* __restrict__ WtO)
{
    __shared__ float tile[32][33];
    const float* src; ushort* dst;
    switch (blockIdx.z) {
        case 0:  src = Wq; dst = WtQKV;                 break;
        case 1:  src = Wk; dst = WtQKV + 1024 * 1024;   break;
        case 2:  src = Wv; dst = WtQKV + 2048 * 1024;   break;
        default: src = Wo; dst = WtO;                   break;
    }
    const int k0 = blockIdx.y * 32, n0 = blockIdx.x * 32;
    const int tx = threadIdx.x & 31, ty = threadIdx.x >> 5;
    #pragma unroll
    for (int i = 0; i < 4; ++i)
        tile[i * 8 + ty][tx] = src[(size_t)(k0 + i * 8 + ty) * 1024 + n0 + tx];
    __syncthreads();
    #pragma unroll
    for (int i = 0; i < 4; ++i)
        dst[(size_t)(n0 + i * 8 + ty) * 1024 + k0 + tx] = f2bf(tile[tx][i * 8 + ty]);
}

// ---------------------------------------------------------------------------
// QKV GEMM (M=4096, N=3072, K=1024), 128x128 tile, BK=64, T2-swizzled LDS.
// Epilogue fuses bias + RoPE (HW v_sin/v_cos on revolutions); Q scaled by
// 0.125*log2(e).  Writes Q->Qb, K->Kb (row-major), V->Vt (transposed).
// ---------------------------------------------------------------------------
__global__ __launch_bounds__(256, 3) void gemm_qkv(
    const ushort* __restrict__ A, const ushort* __restrict__ Bt,
    const float* __restrict__ bq, const float* __restrict__ bk,
    const float* __restrict__ bv,
    ushort* __restrict__ Qb, ushort* __restrict__ Kb, ushort* __restrict__ Vt)
{
    __shared__ ushort As[128 * 64];
    __shared__ ushort Bs[128 * 64];
    const int t = threadIdx.x, w = t >> 6, l = t & 63;
    const int lr = l & 15, lg = l >> 4;
    const int wr = w >> 1, wc = w & 1;
    const int row0 = blockIdx.y * 128, col0 = blockIdx.x * 128;

    f32x4 acc[4][4] = {};

    for (int k0 = 0; k0 < 1024; k0 += 64) {
        #pragma unroll
        for (int i = 0; i < 4; ++i) {
            const int r  = w * 32 + i * 8 + (l >> 3);
            const int cs = ((l & 7) ^ (r & 7)) * 8;          // src pre-swizzle
            gload_lds16(&A [(size_t)(row0 + r) * 1024 + k0 + cs], &As[(w * 32 + i * 8) * 64]);
            gload_lds16(&Bt[(size_t)(col0 + r) * 1024 + k0 + cs], &Bs[(w * 32 + i * 8) * 64]);
        }
        asm volatile("s_waitcnt vmcnt(0)");
        __syncthreads();

        #pragma unroll
        for (int kk = 0; kk < 2; ++kk) {
            bf16x8 af[4], bfr[4];
            #pragma unroll
            for (int m = 0; m < 4; ++m)
                af[m] = *reinterpret_cast<const bf16x8*>(
                    &As[(wr * 64 + m * 16 + lr) * 64 + (((kk * 4 + lg) ^ (lr & 7)) * 8)]);
            #pragma unroll
            for (int n = 0; n < 4; ++n)
                bfr[n] = *reinterpret_cast<const bf16x8*>(
                    &Bs[(wc * 64 + n * 16 + lr) * 64 + (((kk * 4 + lg) ^ (lr & 7)) * 8)]);
            #pragma unroll
            for (int m = 0; m < 4; ++m)
                #pragma unroll
                for (int n = 0; n < 4; ++n)
                    acc[m][n] = __builtin_amdgcn_mfma_f32_16x16x32_bf16(
                        af[m], bfr[n], acc[m][n], 0, 0, 0);
        }
        __syncthreads();
    }

    const int cbase = col0 + wc * 64;          // wave's 64-col span (one head)
    const int cls   = cbase >> 10;             // 0=Q, 1=K, 2=V
    const int hcol  = cbase & 1023;            // head-aligned col within 1024
    const float* bias = (cls == 0) ? bq : (cls == 1 ? bk : bv);

    if (cls < 2) {
        ushort* dst = (cls == 0) ? Qb : Kb;
        const float qscale = (cls == 0) ? 0.1803368801f : 1.0f;  // 0.125*log2(e)
        #pragma unroll
        for (int m = 0; m < 4; ++m) {
            const int rbase = row0 + wr * 64 + m * 16 + lg * 4;
            #pragma unroll
            for (int n = 0; n < 2; ++n) {
                const int i    = n * 16 + lr;                  // 0..31
                const float b0 = bias[hcol + i];
                const float b1 = bias[hcol + i + 32];
                // invf / (2*pi): angle in revolutions = s * invf_rev
                const float invf_rev =
                    exp2f(-(float)i * 0.415241012f) * 0.15915494309f;
                #pragma unroll
                for (int r = 0; r < 4; ++r) {
                    const int row = rbase + r;
                    const int s   = row & (S_ - 1);
                    float sn, cs_;
                    hw_sincos_rev((float)s * invf_rev, &sn, &cs_);
                    const float v0 = acc[m][n][r]     + b0;
                    const float v1 = acc[m][n + 2][r] + b1;
                    dst[(size_t)row * 1024 + hcol + i]      = f2bf((v0 * cs_ - v1 * sn) * qscale);
                    dst[(size_t)row * 1024 + hcol + i + 32] = f2bf((v1 * cs_ + v0 * sn) * qscale);
                }
            }
        }
    } else {
        const int h = hcol >> 6;
        #pragma unroll
        for (int m = 0; m < 4; ++m) {
            const int rbase = row0 + wr * 64 + m * 16 + lg * 4;
            const int bb = rbase >> 11, s0 = rbase & (S_ - 1);
            #pragma unroll
            for (int n = 0; n < 4; ++n) {
                const int d = n * 16 + lr;
                const float bia = bias[hcol + d];
                ushort4v pk;
                #pragma unroll
                for (int r = 0; r < 4; ++r) pk[r] = f2bf(acc[m][n][r] + bia);
                *reinterpret_cast<ushort4v*>(
                    &Vt[((size_t)(bb * 16 + h) * 64 + d) * S_ + s0]) = pk;
            }
        }
    }
}

// ---------------------------------------------------------------------------
// Output GEMM: C[M,1024] f32 = A @ Wt^T + bias
// ---------------------------------------------------------------------------
__global__ __launch_bounds__(256, 1) void gemm_out(
    const ushort* __restrict__ A, const ushort* __restrict__ Bt,
    const float* __restrict__ bias, float* __restrict__ C, int N, int K)
{
    __shared__ ushort As[128 * 64];
    __shared__ ushort Bs[128 * 64];
    const int t = threadIdx.x, w = t >> 6, l = t & 63;
    const int lr = l & 15, lg = l >> 4;
    const int wr = w >> 1, wc = w & 1;
    const int row0 = blockIdx.y * 128, col0 = blockIdx.x * 128;

    f32x4 acc[4][4] = {};

    for (int k0 = 0; k0 < K; k0 += 64) {
        #pragma unroll
        for (int i = 0; i < 4; ++i) {
            const int r  = w * 32 + i * 8 + (l >> 3);
            const int cs = ((l & 7) ^ (r & 7)) * 8;
            gload_lds16(&A [(size_t)(row0 + r) * K + k0 + cs], &As[(w * 32 + i * 8) * 64]);
            gload_lds16(&Bt[(size_t)(col0 + r) * K + k0 + cs], &Bs[(w * 32 + i * 8) * 64]);
        }
        asm volatile("s_waitcnt vmcnt(0)");
        __syncthreads();

        #pragma unroll
        for (int kk = 0; kk < 2; ++kk) {
            bf16x8 af[4], bfr[4];
            #pragma unroll
            for (int m = 0; m < 4; ++m)
                af[m] = *reinterpret_cast<const bf16x8*>(
                    &As[(wr * 64 + m * 16 + lr) * 64 + (((kk * 4 + lg) ^ (lr & 7)) * 8)]);
            #pragma unroll
            for (int n = 0; n < 4; ++n)
                bfr[n] = *reinterpret_cast<const bf16x8*>(
                    &Bs[(wc * 64 + n * 16 + lr) * 64 + (((kk * 4 + lg) ^ (lr & 7)) * 8)]);
            #pragma unroll
            for (int m = 0; m < 4; ++m)
                #pragma unroll
                for (int n = 0; n < 4; ++n)
                    acc[m][n] = __builtin_amdgcn_mfma_f32_16x16x32_bf16(
                        af[m], bfr[n], acc[m][n], 0, 0, 0);
        }
        __syncthreads();
    }

    #pragma unroll
    for (int m = 0; m < 4; ++m) {
        const int rbase = row0 + wr * 64 + m * 16 + lg * 4;
        #pragma unroll
        for (int n = 0; n < 4; ++n) {
            const int c = col0 + wc * 64 + n * 16 + lr;
            const float bv = bias[c];
            #pragma unroll
            for (int r = 0; r < 4; ++r)
                C[(size_t)(rbase + r) * N + c] = acc[m][n][r] + bv;
        }
    }
}

// ---------------------------------------------------------------------------
// attn9: fully wave-independent flash attention.  One wave = one 32-row
// q-tile; K/V fragments read DIRECTLY from L2 (no LDS, no barriers, no
// staging).  Block = 4 independent waves, same bh (L1/L2 locality, XCD =
// bh&7 via dispatch order), balanced qt mapping {2jj, 63-2jj, 62-2jj,
// 2jj+1} -> exactly 66 k-tile iterations per block.  Grid = 512 blocks =
// 2 blocks/CU, all resident.  In-register softmax identical to attn7.
// launch_bounds (256,2): VGPR cap 256 -> NO spill (attn8 lesson).
// ---------------------------------------------------------------------------
__global__ __launch_bounds__(256, 2) void attn9(
    const ushort* __restrict__ Qb, const ushort* __restrict__ Kb,
    const ushort* __restrict__ Vt, ushort* __restrict__ AO)
{
    const int tid = threadIdx.x, w = tid >> 6, l = tid & 63;
    const int lq = l & 31, hi = l >> 5;
    const int bid = blockIdx.x;
    const int bh = bid & 31, b = bh >> 4, h = bh & 15;
    const int jj = bid >> 5;                   // 0..15
    int qt;
    switch (w) {
        case 0:  qt = 2 * jj;      break;      // short
        case 1:  qt = 63 - 2 * jj; break;      // long
        case 2:  qt = 62 - 2 * jj; break;      // long
        default: qt = 2 * jj + 1;  break;      // short
    }
    const int q0 = qt * 32;
    const int qg = q0 + lq;                    // this lane's q row
    const int nt = (q0 + 95) >> 6;             // ceil((q0+32)/64) 64-key tiles

    const ushort* Kbh = Kb + (size_t)b * S_ * 1024 + h * 64 + hi * 8;
    const ushort* Vbh = Vt + (size_t)bh * 64 * S_ + hi * 8;

    // Q fragments (B-operand): qf[dc] = Q[qg][16*dc + 8*hi + j]
    bf16x8 qf[4];
    {
        const ushort* qrow = Qb + (size_t)(b * S_ + qg) * 1024 + h * 64 + 8 * hi;
        #pragma unroll
        for (int dc = 0; dc < 4; ++dc)
            qf[dc] = *reinterpret_cast<const bf16x8*>(qrow + 16 * dc);
    }

    f32x16 oacc[2] = {};                       // O^T: rows=d, col=q(lane)
    float mrow = -3.0e38f, lrow = 0.f;

    for (int t = 0; t < nt; ++t) {
        const int kt = t * 64;

        // ---- K fragments (direct from L2); A-operand rows kt+sub*32+lq ----
        bf16x8 kf[2][4];
        #pragma unroll
        for (int sub = 0; sub < 2; ++sub) {
            const ushort* kr = Kbh + (size_t)(kt + sub * 32 + lq) * 1024;
            #pragma unroll
            for (int dc = 0; dc < 4; ++dc)
                kf[sub][dc] = *reinterpret_cast<const bf16x8*>(kr + dc * 16);
        }
        // ---- V fragments issued early (consumed after softmax) ----
        bf16x8 vf[2][4];
        #pragma unroll
        for (int dt = 0; dt < 2; ++dt) {
            const ushort* vr = Vbh + (size_t)(dt * 32 + lq) * S_ + kt;
            #pragma unroll
            for (int j = 0; j < 4; ++j)
                vf[dt][j] = *reinterpret_cast<const bf16x8*>(vr + j * 16);
        }

        // ---- S^T = K @ Q^T ----
        f32x16 sacc[2] = {};
        __builtin_amdgcn_s_setprio(1);
        #pragma unroll
        for (int sub = 0; sub < 2; ++sub)
            #pragma unroll
            for (int dc = 0; dc < 4; ++dc)
                sacc[sub] = __builtin_amdgcn_mfma_f32_32x32x16_bf16(
                    kf[sub][dc], qf[dc], sacc[sub], 0, 0, 0);
        __builtin_amdgcn_s_setprio(0);

        // ---- causal mask (tail tile only; earlier tiles end <= q0-1) ----
        if (t == nt - 1) {
            #pragma unroll
            for (int sub = 0; sub < 2; ++sub)
                #pragma unroll
                for (int r = 0; r < 16; ++r) {
                    const int kg = kt + sub * 32 + (r & 3) + 8 * (r >> 2) + 4 * hi;
                    if (kg > qg) sacc[sub][r] = -1.0e30f;
                }
        }

        // ---- row max: tree (depth 5) + one cross-half exchange ----
        float mx[16];
        #pragma unroll
        for (int r = 0; r < 16; ++r) mx[r] = fmaxf(sacc[0][r], sacc[1][r]);
        #pragma unroll
        for (int s2 = 8; s2 > 0; s2 >>= 1)
            #pragma unroll
            for (int r = 0; r < s2; ++r) mx[r] = fmaxf(mx[r], mx[r + s2]);
        const float tm = fmaxf(mx[0], __shfl_xor(mx[0], 32));

        // ---- rescale (exact skip when no lane has a new max) ----
        if (!__all(tm <= mrow)) {
            const float mnew = fmaxf(mrow, tm);
            const float corr = hw_exp2(mrow - mnew);
            lrow *= corr;
            #pragma unroll
            for (int r = 0; r < 16; ++r) { oacc[0][r] *= corr; oacc[1][r] *= corr; }
            mrow = mnew;
        }

        // ---- p = exp2(s - m); tree row-sum ----
        float sm[16];
        #pragma unroll
        for (int sub = 0; sub < 2; ++sub)
            #pragma unroll
            for (int r = 0; r < 16; ++r)
                sacc[sub][r] = hw_exp2(sacc[sub][r] - mrow);
        #pragma unroll
        for (int r = 0; r < 16; ++r) sm[r] = sacc[0][r] + sacc[1][r];
        #pragma unroll
        for (int s2 = 8; s2 > 0; s2 >>= 1)
            #pragma unroll
            for (int r = 0; r < s2; ++r) sm[r] += sm[r + s2];
        lrow += sm[0] + __shfl_xor(sm[0], 32);

        // ---- pack P (cvt_pk + permlane32_swap) and O^T += V^T @ P^T ----
        #pragma unroll
        for (int sub = 0; sub < 2; ++sub) {
            u32 wpk[8];
            #pragma unroll
            for (int i = 0; i < 8; ++i)
                wpk[i] = cvtpk_bf16(sacc[sub][2 * i], sacc[sub][2 * i + 1]);
            u32 a0 = wpk[0], b0 = wpk[2];
            u32 a1 = wpk[1], b1 = wpk[3];
            u32 a2 = wpk[4], b2 = wpk[6];
            u32 a3 = wpk[5], b3 = wpk[7];
            asm("v_permlane32_swap_b32 %0, %1" : "+v"(a0), "+v"(b0));
            asm("v_permlane32_swap_b32 %0, %1" : "+v"(a1), "+v"(b1));
            asm("v_permlane32_swap_b32 %0, %1" : "+v"(a2), "+v"(b2));
            asm("v_permlane32_swap_b32 %0, %1" : "+v"(a3), "+v"(b3));
            u32x4 pw0, pw1;
            pw0[0] = a0; pw0[1] = a1; pw0[2] = b0; pw0[3] = b1;
            pw1[0] = a2; pw1[1] = a3; pw1[2] = b2; pw1[3] = b3;
            const bf16x8 pb0 = __builtin_bit_cast(bf16x8, pw0);
            const bf16x8 pb1 = __builtin_bit_cast(bf16x8, pw1);
            __builtin_amdgcn_s_setprio(1);
            #pragma unroll
            for (int dt = 0; dt < 2; ++dt)
                oacc[dt] = __builtin_amdgcn_mfma_f32_32x32x16_bf16(
                    vf[dt][2 * sub], pb0, oacc[dt], 0, 0, 0);
            #pragma unroll
            for (int dt = 0; dt < 2; ++dt)
                oacc[dt] = __builtin_amdgcn_mfma_f32_32x32x16_bf16(
                    vf[dt][2 * sub + 1], pb1, oacc[dt], 0, 0, 0);
            __builtin_amdgcn_s_setprio(0);
        }
    }

    // ---- epilogue: O^T / l -> AO[q][d] (lane's own q row) ----
    const float inv = 1.f / lrow;
    ushort* aorow = AO + (size_t)(b * S_ + qg) * 1024 + h * 64;
    #pragma unroll
    for (int dt = 0; dt < 2; ++dt)
        #pragma unroll
        for (int g = 0; g < 4; ++g) {
            const int d0 = dt * 32 + g * 8 + hi * 4;
            ushort4v pk;
            #pragma unroll
            for (int j = 0; j < 4; ++j) pk[j] = f2bf(oacc[dt][g * 4 + j] * inv);
            *reinterpret_cast<ushort4v*>(&aorow[d0]) = pk;
        }
}

// ---------------------------------------------------------------------------
extern "C" void kernel_launch(void* const* d_in, const int* in_sizes, int n_in,
                              void* d_out, int out_size, void* d_ws, size_t ws_size,
                              hipStream_t stream)
{
    const float* x  = (const float*)d_in[0];
    const float* Wq = (const float*)d_in[2];
    const float* bq = (const float*)d_in[3];
    const float* Wk = (const float*)d_in[4];
    const float* bk = (const float*)d_in[5];
    const float* Wv = (const float*)d_in[6];
    const float* bv = (const float*)d_in[7];
    const float* Wo = (const float*)d_in[8];
    const float* bo = (const float*)d_in[9];
    float* out = (float*)d_out;

    const size_t tok = (size_t)B_ * S_;            // 4096
    ushort* xb    = (ushort*)d_ws;                 // 4M elems
    ushort* WtQKV = xb + tok * E_;                 // 3M
    ushort* WtO   = WtQKV + (size_t)3072 * 1024;   // 1M
    ushort* Qb    = WtO + (size_t)1024 * 1024;     // 4M
    ushort* Kb    = Qb + tok * E_;                 // 4M
    ushort* Vt    = Kb + tok * E_;                 // 4M
    ushort* AO    = Vt + tok * E_;                 // 4M

    cast_x<<<2048, 256, 0, stream>>>(x, xb);
    castT_w<<<dim3(32, 32, 4), 256, 0, stream>>>(Wq, Wk, Wv, Wo, WtQKV, WtO);

    gemm_qkv<<<dim3(24, 32), 256, 0, stream>>>(xb, WtQKV, bq, bk, bv, Qb, Kb, Vt);

    attn9<<<512, 256, 0, stream>>>(Qb, Kb, Vt, AO);

    gemm_out<<<dim3(8, 32), 256, 0, stream>>>(AO, WtO, bo, out, 1024, 1024);
}

// Round 12
// 112.917 us; speedup vs baseline: 1.5661x; 1.1706x over previous
//
#include <hip/hip_runtime.h>
#include <cmath>

#define B_ 2
#define S_ 2048
#define E_ 1024
#define H_ 16
#define D_ 64

typedef __attribute__((ext_vector_type(8)))  short  bf16x8;
typedef __attribute__((ext_vector_type(4)))  float  f32x4;
typedef __attribute__((ext_vector_type(16))) float  f32x16;
typedef __attribute__((ext_vector_type(8)))  unsigned short ushort8;
typedef __attribute__((ext_vector_type(4)))  unsigned short ushort4v;
typedef __attribute__((ext_vector_type(4)))  unsigned int   u32x4;
typedef unsigned int u32;

__device__ __forceinline__ ushort f2bf(float f) {
    u32 u = __float_as_uint(f);
    u32 r = (u + 0x7fffu + ((u >> 16) & 1u)) >> 16;
    return (ushort)r;
}
__device__ __forceinline__ void gload_lds16(const ushort* gp, ushort* lp) {
    auto g = (const __attribute__((address_space(1))) u32*)gp;
    auto l = (__attribute__((address_space(3))) u32*)lp;
    __builtin_amdgcn_global_load_lds(g, l, 16, 0, 0);
}
__device__ __forceinline__ u32 cvtpk_bf16(float lo, float hi) {
    u32 r;
    asm("v_cvt_pk_bf16_f32 %0, %1, %2" : "=v"(r) : "v"(lo), "v"(hi));
    return r;
}
// raw v_exp_f32 (2^x); input always <= 0 here, hw handles -inf -> 0
__device__ __forceinline__ float hw_exp2(float x) {
    float r;
    asm("v_exp_f32 %0, %1" : "=v"(r) : "v"(x));
    return r;
}
// hardware sin/cos of (2*pi*rev); v_fract first keeps input in-domain
__device__ __forceinline__ void hw_sincos_rev(float rev, float* sn, float* cs) {
    float fr;
    asm("v_fract_f32 %0, %1" : "=v"(fr) : "v"(rev));
    asm("v_sin_f32 %0, %1" : "=v"(*sn) : "v"(fr));
    asm("v_cos_f32 %0, %1" : "=v"(*cs) : "v"(fr));
}

// ---------------------------------------------------------------------------
// cast x (f32 -> bf16), 8 elems/thread
// ---------------------------------------------------------------------------
__global__ __launch_bounds__(256) void cast_x(const float* __restrict__ in,
                                              ushort* __restrict__ out) {
    const int idx = blockIdx.x * 256 + threadIdx.x;
    const float4 a = *reinterpret_cast<const float4*>(&in[(size_t)idx * 8]);
    const float4 b = *reinterpret_cast<const float4*>(&in[(size_t)idx * 8 + 4]);
    ushort8 o;
    o[0] = f2bf(a.x); o[1] = f2bf(a.y); o[2] = f2bf(a.z); o[3] = f2bf(a.w);
    o[4] = f2bf(b.x); o[5] = f2bf(b.y); o[6] = f2bf(b.z); o[7] = f2bf(b.w);
    *reinterpret_cast<ushort8*>(&out[(size_t)idx * 8]) = o;
}

// ---------------------------------------------------------------------------
// cast + transpose weights: W[k][n] f32 -> Wt[n][k] bf16  (1024x1024 each)
// ---------------------------------------------------------------------------
__global__ __launch_bounds__(256) void castT_w(
    const float* __restrict__ Wq, const float* __restrict__ Wk,
    const float* __restrict__ Wv, const float* __restrict__ Wo,
    ushort* __restrict__ WtQKV, ushort* __restrict__ WtO)
{
    __shared__ float tile[32][33];
    const float* src; ushort* dst;
    switch (blockIdx.z) {
        case 0:  src = Wq; dst = WtQKV;                 break;
        case 1:  src = Wk; dst = WtQKV + 1024 * 1024;   break;
        case 2:  src = Wv; dst = WtQKV + 2048 * 1024;   break;
        default: src = Wo; dst = WtO;                   break;
    }
    const int k0 = blockIdx.y * 32, n0 = blockIdx.x * 32;
    const int tx = threadIdx.x & 31, ty = threadIdx.x >> 5;
    #pragma unroll
    for (int i = 0; i < 4; ++i)
        tile[i * 8 + ty][tx] = src[(size_t)(k0 + i * 8 + ty) * 1024 + n0 + tx];
    __syncthreads();
    #pragma unroll
    for (int i = 0; i < 4; ++i)
        dst[(size_t)(n0 + i * 8 + ty) * 1024 + k0 + tx] = f2bf(tile[tx][i * 8 + ty]);
}

// ---------------------------------------------------------------------------
// QKV GEMM (M=4096, N=3072, K=1024), 128x128 tile, BK=64, T2-swizzled LDS.
// Single-buffered on purpose: grid 768 = 3 blocks/CU exactly; cross-block
// TLP hides the per-step drain, and dbuf's 64 KB would drop to 2/CU with a
// half-idle tail round.  Epilogue fuses bias + RoPE (HW v_sin/v_cos);
// Q scaled by 0.125*log2(e).  Writes Q->Qb, K->Kb, V->Vt (transposed).
// ---------------------------------------------------------------------------
__global__ __launch_bounds__(256, 3) void gemm_qkv(
    const ushort* __restrict__ A, const ushort* __restrict__ Bt,
    const float* __restrict__ bq, const float* __restrict__ bk,
    const float* __restrict__ bv,
    ushort* __restrict__ Qb, ushort* __restrict__ Kb, ushort* __restrict__ Vt)
{
    __shared__ ushort As[128 * 64];
    __shared__ ushort Bs[128 * 64];
    const int t = threadIdx.x, w = t >> 6, l = t & 63;
    const int lr = l & 15, lg = l >> 4;
    const int wr = w >> 1, wc = w & 1;
    const int row0 = blockIdx.y * 128, col0 = blockIdx.x * 128;

    f32x4 acc[4][4] = {};

    for (int k0 = 0; k0 < 1024; k0 += 64) {
        #pragma unroll
        for (int i = 0; i < 4; ++i) {
            const int r  = w * 32 + i * 8 + (l >> 3);
            const int cs = ((l & 7) ^ (r & 7)) * 8;          // src pre-swizzle
            gload_lds16(&A [(size_t)(row0 + r) * 1024 + k0 + cs], &As[(w * 32 + i * 8) * 64]);
            gload_lds16(&Bt[(size_t)(col0 + r) * 1024 + k0 + cs], &Bs[(w * 32 + i * 8) * 64]);
        }
        asm volatile("s_waitcnt vmcnt(0)");
        __syncthreads();

        #pragma unroll
        for (int kk = 0; kk < 2; ++kk) {
            bf16x8 af[4], bfr[4];
            #pragma unroll
            for (int m = 0; m < 4; ++m)
                af[m] = *reinterpret_cast<const bf16x8*>(
                    &As[(wr * 64 + m * 16 + lr) * 64 + (((kk * 4 + lg) ^ (lr & 7)) * 8)]);
            #pragma unroll
            for (int n = 0; n < 4; ++n)
                bfr[n] = *reinterpret_cast<const bf16x8*>(
                    &Bs[(wc * 64 + n * 16 + lr) * 64 + (((kk * 4 + lg) ^ (lr & 7)) * 8)]);
            #pragma unroll
            for (int m = 0; m < 4; ++m)
                #pragma unroll
                for (int n = 0; n < 4; ++n)
                    acc[m][n] = __builtin_amdgcn_mfma_f32_16x16x32_bf16(
                        af[m], bfr[n], acc[m][n], 0, 0, 0);
        }
        __syncthreads();
    }

    const int cbase = col0 + wc * 64;          // wave's 64-col span (one head)
    const int cls   = cbase >> 10;             // 0=Q, 1=K, 2=V
    const int hcol  = cbase & 1023;            // head-aligned col within 1024
    const float* bias = (cls == 0) ? bq : (cls == 1 ? bk : bv);

    if (cls < 2) {
        ushort* dst = (cls == 0) ? Qb : Kb;
        const float qscale = (cls == 0) ? 0.1803368801f : 1.0f;  // 0.125*log2(e)
        #pragma unroll
        for (int m = 0; m < 4; ++m) {
            const int rbase = row0 + wr * 64 + m * 16 + lg * 4;
            #pragma unroll
            for (int n = 0; n < 2; ++n) {
                const int i    = n * 16 + lr;                  // 0..31
                const float b0 = bias[hcol + i];
                const float b1 = bias[hcol + i + 32];
                // invf / (2*pi): angle in revolutions = s * invf_rev
                const float invf_rev =
                    exp2f(-(float)i * 0.415241012f) * 0.15915494309f;
                #pragma unroll
                for (int r = 0; r < 4; ++r) {
                    const int row = rbase + r;
                    const int s   = row & (S_ - 1);
                    float sn, cs_;
                    hw_sincos_rev((float)s * invf_rev, &sn, &cs_);
                    const float v0 = acc[m][n][r]     + b0;
                    const float v1 = acc[m][n + 2][r] + b1;
                    dst[(size_t)row * 1024 + hcol + i]      = f2bf((v0 * cs_ - v1 * sn) * qscale);
                    dst[(size_t)row * 1024 + hcol + i + 32] = f2bf((v1 * cs_ + v0 * sn) * qscale);
                }
            }
        }
    } else {
        const int h = hcol >> 6;
        #pragma unroll
        for (int m = 0; m < 4; ++m) {
            const int rbase = row0 + wr * 64 + m * 16 + lg * 4;
            const int bb = rbase >> 11, s0 = rbase & (S_ - 1);
            #pragma unroll
            for (int n = 0; n < 4; ++n) {
                const int d = n * 16 + lr;
                const float bia = bias[hcol + d];
                ushort4v pk;
                #pragma unroll
                for (int r = 0; r < 4; ++r) pk[r] = f2bf(acc[m][n][r] + bia);
                *reinterpret_cast<ushort4v*>(
                    &Vt[((size_t)(bb * 16 + h) * 64 + d) * S_ + s0]) = pk;
            }
        }
    }
}

// ---------------------------------------------------------------------------
// Output GEMM: C[M,1024] f32 = A @ Wt^T + bias.
// Grid = 256 blocks = 1 block/CU: no cross-block TLP, so the per-K-step
// barrier drain was fully exposed.  Now: double-buffered LDS + counted
// vmcnt(8) + raw s_barrier (attn7's verified pattern) -> next tile's 8
// global_load_lds stay in flight across the barrier.
// ---------------------------------------------------------------------------
__global__ __launch_bounds__(256, 1) void gemm_out(
    const ushort* __restrict__ A, const ushort* __restrict__ Bt,
    const float* __restrict__ bias, float* __restrict__ C, int N, int K)
{
    __shared__ ushort As[2][128 * 64];
    __shared__ ushort Bs[2][128 * 64];
    const int t = threadIdx.x, w = t >> 6, l = t & 63;
    const int lr = l & 15, lg = l >> 4;
    const int wr = w >> 1, wc = w & 1;
    const int row0 = blockIdx.y * 128, col0 = blockIdx.x * 128;

    f32x4 acc[4][4] = {};

    auto STAGE = [&](int buf, int k0) {
        #pragma unroll
        for (int i = 0; i < 4; ++i) {
            const int r  = w * 32 + i * 8 + (l >> 3);
            const int cs = ((l & 7) ^ (r & 7)) * 8;
            gload_lds16(&A [(size_t)(row0 + r) * K + k0 + cs], &As[buf][(w * 32 + i * 8) * 64]);
            gload_lds16(&Bt[(size_t)(col0 + r) * K + k0 + cs], &Bs[buf][(w * 32 + i * 8) * 64]);
        }
    };

    STAGE(0, 0);
    int cur = 0;

    for (int k0 = 0; k0 < K; k0 += 64) {
        if (k0 + 64 < K) {
            STAGE(cur ^ 1, k0 + 64);
            asm volatile("s_waitcnt vmcnt(8)" ::: "memory");  // current tile only
        } else {
            asm volatile("s_waitcnt vmcnt(0)" ::: "memory");
        }
        __builtin_amdgcn_s_barrier();

        #pragma unroll
        for (int kk = 0; kk < 2; ++kk) {
            bf16x8 af[4], bfr[4];
            #pragma unroll
            for (int m = 0; m < 4; ++m)
                af[m] = *reinterpret_cast<const bf16x8*>(
                    &As[cur][(wr * 64 + m * 16 + lr) * 64 + (((kk * 4 + lg) ^ (lr & 7)) * 8)]);
            #pragma unroll
            for (int n = 0; n < 4; ++n)
                bfr[n] = *reinterpret_cast<const bf16x8*>(
                    &Bs[cur][(wc * 64 + n * 16 + lr) * 64 + (((kk * 4 + lg) ^ (lr & 7)) * 8)]);
            #pragma unroll
            for (int m = 0; m < 4; ++m)
                #pragma unroll
                for (int n = 0; n < 4; ++n)
                    acc[m][n] = __builtin_amdgcn_mfma_f32_16x16x32_bf16(
                        af[m], bfr[n], acc[m][n], 0, 0, 0);
        }
        __builtin_amdgcn_s_barrier();          // reads of cur done before reuse
        cur ^= 1;
    }

    #pragma unroll
    for (int m = 0; m < 4; ++m) {
        const int rbase = row0 + wr * 64 + m * 16 + lg * 4;
        #pragma unroll
        for (int n = 0; n < 4; ++n) {
            const int c = col0 + wc * 64 + n * 16 + lr;
            const float bv = bias[c];
            #pragma unroll
            for (int r = 0; r < 4; ++r)
                C[(size_t)(rbase + r) * N + c] = acc[m][n][r] + bv;
        }
    }
}

// ---------------------------------------------------------------------------
// attn7 (reverted best, 57.7 us): LDS-shared K/V (q-block = 64 rows, 2 waves
// x 32 rows), dbuf + counted vmcnt + raw s_barrier, in-register softmax
// (swapped operands), tree reductions, exact defer-max, cvt_pk+permlane pack.
// ---------------------------------------------------------------------------
__global__ __launch_bounds__(128, 2) void attn7(
    const ushort* __restrict__ Qb, const ushort* __restrict__ Kb,
    const ushort* __restrict__ Vt, ushort* __restrict__ AO)
{
    __shared__ ushort Ks[2][64 * 64];
    __shared__ ushort Vs[2][64 * 64];

    const int t = threadIdx.x, w = t >> 6, l = t & 63;
    const int lq = l & 31, hi = l >> 5;
    const int idx = blockIdx.x;
    const int bh = idx & 31, b = bh >> 4, h = bh & 15;
    const int qt = 31 - (idx >> 5);            // longest q-tiles dispatch first
    const int q0 = qt * 64, qw = q0 + w * 32;
    const int qg = qw + lq;                    // this lane's q row

    const ushort* Kbh = Kb + (size_t)b * S_ * 1024 + h * 64;
    const ushort* Vbh = Vt + (size_t)bh * 64 * S_;

    // Q fragments (B-operand): qf[dc] = Q[qg][16*dc + 8*hi + j]
    bf16x8 qf[4];
    {
        const ushort* qrow = Qb + (size_t)(b * S_ + qg) * 1024 + h * 64 + 8 * hi;
        #pragma unroll
        for (int dc = 0; dc < 4; ++dc)
            qf[dc] = *reinterpret_cast<const bf16x8*>(qrow + 16 * dc);
    }

    f32x16 oacc[2] = {};                       // O^T: rows=d, col=q(lane)
    float mrow = -3.0e38f, lrow = 0.f;

    auto STAGE = [&](int buf, int kt) {
        #pragma unroll
        for (int i = 0; i < 4; ++i) {
            const int cid = i * 128 + t;                     // 0..511
            const int r   = cid >> 3;                        // 0..63
            const int cs  = ((cid & 7) ^ (r & 7)) * 8;       // src pre-swizzle
            const int db  = (i * 128 + w * 64) * 8;          // wave-uniform dest
            gload_lds16(&Kbh[(size_t)(kt + r) * 1024 + cs], &Ks[buf][db]);
            gload_lds16(&Vbh[(size_t)r * S_ + kt + cs],     &Vs[buf][db]);
        }
    };

    const int kend = q0 + 64;
    STAGE(0, 0);
    int cur = 0;

    for (int kt = 0; kt < kend; kt += 64) {
        if (kt + 64 < kend) {
            STAGE(cur ^ 1, kt + 64);
            asm volatile("s_waitcnt vmcnt(8)" ::: "memory");
        } else {
            asm volatile("s_waitcnt vmcnt(0)" ::: "memory");
        }
        __builtin_amdgcn_s_barrier();

        {
            const ushort* Kc = &Ks[cur][0];
            const ushort* Vc = &Vs[cur][0];

            // ---- S^T = K @ Q^T (K frags from swizzled LDS) ----
            f32x16 sacc[2] = {};
            #pragma unroll
            for (int sub = 0; sub < 2; ++sub) {
                const int rK = sub * 32 + lq;
                const int rx = rK & 7;
                __builtin_amdgcn_s_setprio(1);
                #pragma unroll
                for (int dc = 0; dc < 4; ++dc) {
                    const bf16x8 kf = *reinterpret_cast<const bf16x8*>(
                        &Kc[rK * 64 + (((2 * dc + hi) ^ rx) * 8)]);
                    sacc[sub] = __builtin_amdgcn_mfma_f32_32x32x16_bf16(
                        kf, qf[dc], sacc[sub], 0, 0, 0);
                }
                __builtin_amdgcn_s_setprio(0);
            }

            // ---- V frags issued early (lgkm latency hides under softmax) ----
            bf16x8 vf[2][2][2];
            #pragma unroll
            for (int dt = 0; dt < 2; ++dt) {
                const int rV = dt * 32 + lq;
                const int rx = rV & 7;
                #pragma unroll
                for (int sub = 0; sub < 2; ++sub)
                    #pragma unroll
                    for (int kc = 0; kc < 2; ++kc)
                        vf[dt][sub][kc] = *reinterpret_cast<const bf16x8*>(
                            &Vc[rV * 64 + (((4 * sub + 2 * kc + hi) ^ rx) * 8)]);
            }

            // ---- causal mask (boundary tiles only) ----
            #pragma unroll
            for (int sub = 0; sub < 2; ++sub)
                if (kt + sub * 32 + 31 > qw) {
                    #pragma unroll
                    for (int r = 0; r < 16; ++r) {
                        const int kg = kt + sub * 32 + (r & 3) + 8 * (r >> 2) + 4 * hi;
                        if (kg > qg) sacc[sub][r] = -1.0e30f;
                    }
                }

            // ---- row max: tree (depth 5) + one cross-half exchange ----
            float mx[16];
            #pragma unroll
            for (int r = 0; r < 16; ++r) mx[r] = fmaxf(sacc[0][r], sacc[1][r]);
            #pragma unroll
            for (int s2 = 8; s2 > 0; s2 >>= 1)
                #pragma unroll
                for (int r = 0; r < s2; ++r) mx[r] = fmaxf(mx[r], mx[r + s2]);
            const float tm = fmaxf(mx[0], __shfl_xor(mx[0], 32));

            // ---- rescale (exact skip when no lane has a new max) ----
            if (!__all(tm <= mrow)) {
                const float mnew = fmaxf(mrow, tm);
                const float corr = hw_exp2(mrow - mnew);
                lrow *= corr;
                #pragma unroll
                for (int r = 0; r < 16; ++r) { oacc[0][r] *= corr; oacc[1][r] *= corr; }
                mrow = mnew;
            }

            // ---- p = exp2(s - m); tree row-sum ----
            float sm[16];
            #pragma unroll
            for (int sub = 0; sub < 2; ++sub)
                #pragma unroll
                for (int r = 0; r < 16; ++r)
                    sacc[sub][r] = hw_exp2(sacc[sub][r] - mrow);
            #pragma unroll
            for (int r = 0; r < 16; ++r) sm[r] = sacc[0][r] + sacc[1][r];
            #pragma unroll
            for (int s2 = 8; s2 > 0; s2 >>= 1)
                #pragma unroll
                for (int r = 0; r < s2; ++r) sm[r] += sm[r + s2];
            lrow += sm[0] + __shfl_xor(sm[0], 32);

            // ---- pack P (cvt_pk + permlane32_swap) and O^T += V^T @ P^T ----
            #pragma unroll
            for (int sub = 0; sub < 2; ++sub) {
                u32 wpk[8];
                #pragma unroll
                for (int i = 0; i < 8; ++i)
                    wpk[i] = cvtpk_bf16(sacc[sub][2 * i], sacc[sub][2 * i + 1]);
                u32 a0 = wpk[0], b0 = wpk[2];
                u32 a1 = wpk[1], b1 = wpk[3];
                u32 a2 = wpk[4], b2 = wpk[6];
                u32 a3 = wpk[5], b3 = wpk[7];
                asm("v_permlane32_swap_b32 %0, %1" : "+v"(a0), "+v"(b0));
                asm("v_permlane32_swap_b32 %0, %1" : "+v"(a1), "+v"(b1));
                asm("v_permlane32_swap_b32 %0, %1" : "+v"(a2), "+v"(b2));
                asm("v_permlane32_swap_b32 %0, %1" : "+v"(a3), "+v"(b3));
                u32x4 pw0, pw1;
                pw0[0] = a0; pw0[1] = a1; pw0[2] = b0; pw0[3] = b1;
                pw1[0] = a2; pw1[1] = a3; pw1[2] = b2; pw1[3] = b3;
                const bf16x8 pb0 = __builtin_bit_cast(bf16x8, pw0);
                const bf16x8 pb1 = __builtin_bit_cast(bf16x8, pw1);
                __builtin_amdgcn_s_setprio(1);
                #pragma unroll
                for (int dt = 0; dt < 2; ++dt)
                    oacc[dt] = __builtin_amdgcn_mfma_f32_32x32x16_bf16(
                        vf[dt][sub][0], pb0, oacc[dt], 0, 0, 0);
                #pragma unroll
                for (int dt = 0; dt < 2; ++dt)
                    oacc[dt] = __builtin_amdgcn_mfma_f32_32x32x16_bf16(
                        vf[dt][sub][1], pb1, oacc[dt], 0, 0, 0);
                __builtin_amdgcn_s_setprio(0);
            }
        }
        __builtin_amdgcn_s_barrier();
        cur ^= 1;
    }

    // ---- epilogue: O^T / l -> AO[q][d] (lane's own q row) ----
    const float inv = 1.f / lrow;
    ushort* aorow = AO + (size_t)(b * S_ + qg) * 1024 + h * 64;
    #pragma unroll
    for (int dt = 0; dt < 2; ++dt)
        #pragma unroll
        for (int g = 0; g < 4; ++g) {
            const int d0 = dt * 32 + g * 8 + hi * 4;
            ushort4v pk;
            #pragma unroll
            for (int j = 0; j < 4; ++j) pk[j] = f2bf(oacc[dt][g * 4 + j] * inv);
            *reinterpret_cast<ushort4v*>(&aorow[d0]) = pk;
        }
}

// ---------------------------------------------------------------------------
extern "C" void kernel_launch(void* const* d_in, const int* in_sizes, int n_in,
                              void* d_out, int out_size, void* d_ws, size_t ws_size,
                              hipStream_t stream)
{
    const float* x  = (const float*)d_in[0];
    const float* Wq = (const float*)d_in[2];
    const float* bq = (const float*)d_in[3];
    const float* Wk = (const float*)d_in[4];
    const float* bk = (const float*)d_in[5];
    const float* Wv = (const float*)d_in[6];
    const float* bv = (const float*)d_in[7];
    const float* Wo = (const float*)d_in[8];
    const float* bo = (const float*)d_in[9];
    float* out = (float*)d_out;

    const size_t tok = (size_t)B_ * S_;            // 4096
    ushort* xb    = (ushort*)d_ws;                 // 4M elems
    ushort* WtQKV = xb + tok * E_;                 // 3M
    ushort* WtO   = WtQKV + (size_t)3072 * 1024;   // 1M
    ushort* Qb    = WtO + (size_t)1024 * 1024;     // 4M
    ushort* Kb    = Qb + tok * E_;                 // 4M
    ushort* Vt    = Kb + tok * E_;                 // 4M
    ushort* AO    = Vt + tok * E_;                 // 4M

    cast_x<<<2048, 256, 0, stream>>>(x, xb);
    castT_w<<<dim3(32, 32, 4), 256, 0, stream>>>(Wq, Wk, Wv, Wo, WtQKV, WtO);

    gemm_qkv<<<dim3(24, 32), 256, 0, stream>>>(xb, WtQKV, bq, bk, bv, Qb, Kb, Vt);

    attn7<<<1024, 128, 0, stream>>>(Qb, Kb, Vt, AO);

    gemm_out<<<dim3(8, 32), 256, 0, stream>>>(AO, WtO, bo, out, 1024, 1024);
}

// Round 13
// 107.276 us; speedup vs baseline: 1.6485x; 1.0526x over previous
//
#include <hip/hip_runtime.h>
#include <cmath>

#define B_ 2
#define S_ 2048
#define E_ 1024
#define H_ 16
#define D_ 64

typedef __attribute__((ext_vector_type(8)))  short  bf16x8;
typedef __attribute__((ext_vector_type(4)))  float  f32x4;
typedef __attribute__((ext_vector_type(16))) float  f32x16;
typedef __attribute__((ext_vector_type(8)))  unsigned short ushort8;
typedef __attribute__((ext_vector_type(4)))  unsigned short ushort4v;
typedef __attribute__((ext_vector_type(4)))  unsigned int   u32x4;
typedef unsigned int u32;

__device__ __forceinline__ ushort f2bf(float f) {
    u32 u = __float_as_uint(f);
    u32 r = (u + 0x7fffu + ((u >> 16) & 1u)) >> 16;
    return (ushort)r;
}
__device__ __forceinline__ void gload_lds16(const ushort* gp, ushort* lp) {
    auto g = (const __attribute__((address_space(1))) u32*)gp;
    auto l = (__attribute__((address_space(3))) u32*)lp;
    __builtin_amdgcn_global_load_lds(g, l, 16, 0, 0);
}
__device__ __forceinline__ u32 cvtpk_bf16(float lo, float hi) {
    u32 r;
    asm("v_cvt_pk_bf16_f32 %0, %1, %2" : "=v"(r) : "v"(lo), "v"(hi));
    return r;
}
// raw v_exp_f32 (2^x); input always <= 0 here, hw handles -inf -> 0
__device__ __forceinline__ float hw_exp2(float x) {
    float r;
    asm("v_exp_f32 %0, %1" : "=v"(r) : "v"(x));
    return r;
}
// hardware sin/cos of (2*pi*rev); v_fract first keeps input in-domain
__device__ __forceinline__ void hw_sincos_rev(float rev, float* sn, float* cs) {
    float fr;
    asm("v_fract_f32 %0, %1" : "=v"(fr) : "v"(rev));
    asm("v_sin_f32 %0, %1" : "=v"(*sn) : "v"(fr));
    asm("v_cos_f32 %0, %1" : "=v"(*cs) : "v"(fr));
}

// ---------------------------------------------------------------------------
// cast x (f32 -> bf16), 8 elems/thread
// ---------------------------------------------------------------------------
__global__ __launch_bounds__(256) void cast_x(const float* __restrict__ in,
                                              ushort* __restrict__ out) {
    const int idx = blockIdx.x * 256 + threadIdx.x;
    const float4 a = *reinterpret_cast<const float4*>(&in[(size_t)idx * 8]);
    const float4 b = *reinterpret_cast<const float4*>(&in[(size_t)idx * 8 + 4]);
    ushort8 o;
    o[0] = f2bf(a.x); o[1] = f2bf(a.y); o[2] = f2bf(a.z); o[3] = f2bf(a.w);
    o[4] = f2bf(b.x); o[5] = f2bf(b.y); o[6] = f2bf(b.z); o[7] = f2bf(b.w);
    *reinterpret_cast<ushort8*>(&out[(size_t)idx * 8]) = o;
}

// ---------------------------------------------------------------------------
// cast + transpose weights: W[k][n] f32 -> Wt[n][k] bf16  (1024x1024 each)
// ---------------------------------------------------------------------------
__global__ __launch_bounds__(256) void castT_w(
    const float* __restrict__ Wq, const float* __restrict__ Wk,
    const float* __restrict__ Wv, const float* __restrict__ Wo,
    ushort* __restrict__ WtQKV, ushort* __restrict__ WtO)
{
    __shared__ float tile[32][33];
    const float* src; ushort* dst;
    switch (blockIdx.z) {
        case 0:  src = Wq; dst = WtQKV;                 break;
        case 1:  src = Wk; dst = WtQKV + 1024 * 1024;   break;
        case 2:  src = Wv; dst = WtQKV + 2048 * 1024;   break;
        default: src = Wo; dst = WtO;                   break;
    }
    const int k0 = blockIdx.y * 32, n0 = blockIdx.x * 32;
    const int tx = threadIdx.x & 31, ty = threadIdx.x >> 5;
    #pragma unroll
    for (int i = 0; i < 4; ++i)
        tile[i * 8 + ty][tx] = src[(size_t)(k0 + i * 8 + ty) * 1024 + n0 + tx];
    __syncthreads();
    #pragma unroll
    for (int i = 0; i < 4; ++i)
        dst[(size_t)(n0 + i * 8 + ty) * 1024 + k0 + tx] = f2bf(tile[tx][i * 8 + ty]);
}

// ---------------------------------------------------------------------------
// QKV GEMM (M=4096, N=3072, K=1024), 128x128 tile, BK=64, T2-swizzled LDS.
// Epilogue fuses bias + RoPE (HW v_sin/v_cos); Q scaled by 0.125*log2(e).
// Writes Q->Qb, K->Kb (row-major), V->Vt (transposed).
// ---------------------------------------------------------------------------
__global__ __launch_bounds__(256, 3) void gemm_qkv(
    const ushort* __restrict__ A, const ushort* __restrict__ Bt,
    const float* __restrict__ bq, const float* __restrict__ bk,
    const float* __restrict__ bv,
    ushort* __restrict__ Qb, ushort* __restrict__ Kb, ushort* __restrict__ Vt)
{
    __shared__ ushort As[128 * 64];
    __shared__ ushort Bs[128 * 64];
    const int t = threadIdx.x, w = t >> 6, l = t & 63;
    const int lr = l & 15, lg = l >> 4;
    const int wr = w >> 1, wc = w & 1;
    const int row0 = blockIdx.y * 128, col0 = blockIdx.x * 128;

    f32x4 acc[4][4] = {};

    for (int k0 = 0; k0 < 1024; k0 += 64) {
        #pragma unroll
        for (int i = 0; i < 4; ++i) {
            const int r  = w * 32 + i * 8 + (l >> 3);
            const int cs = ((l & 7) ^ (r & 7)) * 8;          // src pre-swizzle
            gload_lds16(&A [(size_t)(row0 + r) * 1024 + k0 + cs], &As[(w * 32 + i * 8) * 64]);
            gload_lds16(&Bt[(size_t)(col0 + r) * 1024 + k0 + cs], &Bs[(w * 32 + i * 8) * 64]);
        }
        asm volatile("s_waitcnt vmcnt(0)");
        __syncthreads();

        #pragma unroll
        for (int kk = 0; kk < 2; ++kk) {
            bf16x8 af[4], bfr[4];
            #pragma unroll
            for (int m = 0; m < 4; ++m)
                af[m] = *reinterpret_cast<const bf16x8*>(
                    &As[(wr * 64 + m * 16 + lr) * 64 + (((kk * 4 + lg) ^ (lr & 7)) * 8)]);
            #pragma unroll
            for (int n = 0; n < 4; ++n)
                bfr[n] = *reinterpret_cast<const bf16x8*>(
                    &Bs[(wc * 64 + n * 16 + lr) * 64 + (((kk * 4 + lg) ^ (lr & 7)) * 8)]);
            #pragma unroll
            for (int m = 0; m < 4; ++m)
                #pragma unroll
                for (int n = 0; n < 4; ++n)
                    acc[m][n] = __builtin_amdgcn_mfma_f32_16x16x32_bf16(
                        af[m], bfr[n], acc[m][n], 0, 0, 0);
        }
        __syncthreads();
    }

    const int cbase = col0 + wc * 64;          // wave's 64-col span (one head)
    const int cls   = cbase >> 10;             // 0=Q, 1=K, 2=V
    const int hcol  = cbase & 1023;            // head-aligned col within 1024
    const float* bias = (cls == 0) ? bq : (cls == 1 ? bk : bv);

    if (cls < 2) {
        ushort* dst = (cls == 0) ? Qb : Kb;
        const float qscale = (cls == 0) ? 0.1803368801f : 1.0f;  // 0.125*log2(e)
        #pragma unroll
        for (int m = 0; m < 4; ++m) {
            const int rbase = row0 + wr * 64 + m * 16 + lg * 4;
            #pragma unroll
            for (int n = 0; n < 2; ++n) {
                const int i    = n * 16 + lr;                  // 0..31
                const float b0 = bias[hcol + i];
                const float b1 = bias[hcol + i + 32];
                // invf / (2*pi): angle in revolutions = s * invf_rev
                const float invf_rev =
                    exp2f(-(float)i * 0.415241012f) * 0.15915494309f;
                #pragma unroll
                for (int r = 0; r < 4; ++r) {
                    const int row = rbase + r;
                    const int s   = row & (S_ - 1);
                    float sn, cs_;
                    hw_sincos_rev((float)s * invf_rev, &sn, &cs_);
                    const float v0 = acc[m][n][r]     + b0;
                    const float v1 = acc[m][n + 2][r] + b1;
                    dst[(size_t)row * 1024 + hcol + i]      = f2bf((v0 * cs_ - v1 * sn) * qscale);
                    dst[(size_t)row * 1024 + hcol + i + 32] = f2bf((v1 * cs_ + v0 * sn) * qscale);
                }
            }
        }
    } else {
        const int h = hcol >> 6;
        #pragma unroll
        for (int m = 0; m < 4; ++m) {
            const int rbase = row0 + wr * 64 + m * 16 + lg * 4;
            const int bb = rbase >> 11, s0 = rbase & (S_ - 1);
            #pragma unroll
            for (int n = 0; n < 4; ++n) {
                const int d = n * 16 + lr;
                const float bia = bias[hcol + d];
                ushort4v pk;
                #pragma unroll
                for (int r = 0; r < 4; ++r) pk[r] = f2bf(acc[m][n][r] + bia);
                *reinterpret_cast<ushort4v*>(
                    &Vt[((size_t)(bb * 16 + h) * 64 + d) * S_ + s0]) = pk;
            }
        }
    }
}

// ---------------------------------------------------------------------------
// Output GEMM: C[M,1024] f32 = A @ Wt^T + bias.  Dbuf + counted vmcnt(8) +
// raw s_barrier (1 block/CU -> drain was fully exposed; verified win r12).
// ---------------------------------------------------------------------------
__global__ __launch_bounds__(256, 1) void gemm_out(
    const ushort* __restrict__ A, const ushort* __restrict__ Bt,
    const float* __restrict__ bias, float* __restrict__ C, int N, int K)
{
    __shared__ ushort As[2][128 * 64];
    __shared__ ushort Bs[2][128 * 64];
    const int t = threadIdx.x, w = t >> 6, l = t & 63;
    const int lr = l & 15, lg = l >> 4;
    const int wr = w >> 1, wc = w & 1;
    const int row0 = blockIdx.y * 128, col0 = blockIdx.x * 128;

    f32x4 acc[4][4] = {};

    auto STAGE = [&](int buf, int k0) {
        #pragma unroll
        for (int i = 0; i < 4; ++i) {
            const int r  = w * 32 + i * 8 + (l >> 3);
            const int cs = ((l & 7) ^ (r & 7)) * 8;
            gload_lds16(&A [(size_t)(row0 + r) * K + k0 + cs], &As[buf][(w * 32 + i * 8) * 64]);
            gload_lds16(&Bt[(size_t)(col0 + r) * K + k0 + cs], &Bs[buf][(w * 32 + i * 8) * 64]);
        }
    };

    STAGE(0, 0);
    int cur = 0;

    for (int k0 = 0; k0 < K; k0 += 64) {
        if (k0 + 64 < K) {
            STAGE(cur ^ 1, k0 + 64);
            asm volatile("s_waitcnt vmcnt(8)" ::: "memory");
        } else {
            asm volatile("s_waitcnt vmcnt(0)" ::: "memory");
        }
        __builtin_amdgcn_s_barrier();

        #pragma unroll
        for (int kk = 0; kk < 2; ++kk) {
            bf16x8 af[4], bfr[4];
            #pragma unroll
            for (int m = 0; m < 4; ++m)
                af[m] = *reinterpret_cast<const bf16x8*>(
                    &As[cur][(wr * 64 + m * 16 + lr) * 64 + (((kk * 4 + lg) ^ (lr & 7)) * 8)]);
            #pragma unroll
            for (int n = 0; n < 4; ++n)
                bfr[n] = *reinterpret_cast<const bf16x8*>(
                    &Bs[cur][(wc * 64 + n * 16 + lr) * 64 + (((kk * 4 + lg) ^ (lr & 7)) * 8)]);
            #pragma unroll
            for (int m = 0; m < 4; ++m)
                #pragma unroll
                for (int n = 0; n < 4; ++n)
                    acc[m][n] = __builtin_amdgcn_mfma_f32_16x16x32_bf16(
                        af[m], bfr[n], acc[m][n], 0, 0, 0);
        }
        __builtin_amdgcn_s_barrier();
        cur ^= 1;
    }

    #pragma unroll
    for (int m = 0; m < 4; ++m) {
        const int rbase = row0 + wr * 64 + m * 16 + lg * 4;
        #pragma unroll
        for (int n = 0; n < 4; ++n) {
            const int c = col0 + wc * 64 + n * 16 + lr;
            const float bv = bias[c];
            #pragma unroll
            for (int r = 0; r < 4; ++r)
                C[(size_t)(rbase + r) * N + c] = acc[m][n][r] + bv;
        }
    }
}

// ---------------------------------------------------------------------------
// attn10: KVBLK=128 to halve the serial iteration depth (F amortization).
// Block = (bh, 128 q-rows) with 4 waves x 32 rows; K[128][64] + V[64][128]
// double-buffered (64 KB) -> 2 blocks/CU, grid 512 all-resident.  Per-tile
// machinery = attn7's, per 32-key sub (4 subs/tile): swizzled LDS reads,
// in-register softmax (swapped operands), tree reductions over 64 scores,
// exact defer-max, cvt_pk+permlane pack.  Counted vmcnt(8) + raw barriers.
// V frags loaded per-sub (scoped) to stay under the 256-VGPR cap (no spill).
// ---------------------------------------------------------------------------
__global__ __launch_bounds__(256, 2) void attn10(
    const ushort* __restrict__ Qb, const ushort* __restrict__ Kb,
    const ushort* __restrict__ Vt, ushort* __restrict__ AO)
{
    __shared__ ushort Ks[2][128 * 64];
    __shared__ ushort Vs[2][64 * 128];

    const int t = threadIdx.x, w = t >> 6, l = t & 63;
    const int lq = l & 31, hi = l >> 5;
    const int idx = blockIdx.x;
    const int bh = idx & 31, b = bh >> 4, h = bh & 15;
    const int qb = 15 - (idx >> 5);            // longest blocks dispatch first
    const int q0 = qb * 128, qw = q0 + w * 32;
    const int qg = qw + lq;                    // this lane's q row

    const ushort* Kbh = Kb + (size_t)b * S_ * 1024 + h * 64;
    const ushort* Vbh = Vt + (size_t)bh * 64 * S_;

    // Q fragments (B-operand): qf[dc] = Q[qg][16*dc + 8*hi + j]
    bf16x8 qf[4];
    {
        const ushort* qrow = Qb + (size_t)(b * S_ + qg) * 1024 + h * 64 + 8 * hi;
        #pragma unroll
        for (int dc = 0; dc < 4; ++dc)
            qf[dc] = *reinterpret_cast<const bf16x8*>(qrow + 16 * dc);
    }

    f32x16 oacc[2] = {};                       // O^T: rows=d, col=q(lane)
    float mrow = -3.0e38f, lrow = 0.f;

    auto STAGE = [&](int buf, int kt) {
        // K: 128 keys x 64 d, 16 KB -> 4 instrs.  Linear dest, pre-swizzled src.
        #pragma unroll
        for (int i = 0; i < 4; ++i) {
            const int cid = i * 256 + t;                     // 0..1023
            const int r   = cid >> 3;                        // key 0..127
            const int cs  = ((cid & 7) ^ (r & 7)) * 8;
            const int db  = (i * 256 + w * 64) * 8;          // wave-uniform dest
            gload_lds16(&Kbh[(size_t)(kt + r) * 1024 + cs], &Ks[buf][db]);
        }
        // V: 64 d x 128 keys, 16 KB -> 4 instrs.  16-chunk XOR swizzle.
        #pragma unroll
        for (int i = 0; i < 4; ++i) {
            const int cid = i * 256 + t;
            const int d   = cid >> 4;                        // 0..63
            const int cs  = ((cid & 15) ^ (d & 15)) * 8;
            const int db  = (i * 256 + w * 64) * 8;
            gload_lds16(&Vbh[(size_t)d * S_ + kt + cs], &Vs[buf][db]);
        }
    };

    const int kend = q0 + 128;
    STAGE(0, 0);
    int cur = 0;

    for (int kt = 0; kt < kend; kt += 128) {
        if (kt + 128 < kend) {
            STAGE(cur ^ 1, kt + 128);
            asm volatile("s_waitcnt vmcnt(8)" ::: "memory");  // current tile only
        } else {
            asm volatile("s_waitcnt vmcnt(0)" ::: "memory");
        }
        __builtin_amdgcn_s_barrier();

        {
            const ushort* Kc = &Ks[cur][0];
            const ushort* Vc = &Vs[cur][0];

            // ---- S^T = K @ Q^T over 128 keys (4 subs of 32) ----
            f32x16 sacc[4] = {};
            #pragma unroll
            for (int sub = 0; sub < 4; ++sub) {
                const int rK = sub * 32 + lq;
                const int rx = lq & 7;
                __builtin_amdgcn_s_setprio(1);
                #pragma unroll
                for (int dc = 0; dc < 4; ++dc) {
                    const bf16x8 kf = *reinterpret_cast<const bf16x8*>(
                        &Kc[rK * 64 + (((2 * dc + hi) ^ rx) * 8)]);
                    sacc[sub] = __builtin_amdgcn_mfma_f32_32x32x16_bf16(
                        kf, qf[dc], sacc[sub], 0, 0, 0);
                }
                __builtin_amdgcn_s_setprio(0);
            }

            // ---- causal mask (boundary subs only; full-masked subs -> p=0) ----
            #pragma unroll
            for (int sub = 0; sub < 4; ++sub)
                if (kt + sub * 32 + 31 > qw) {
                    #pragma unroll
                    for (int r = 0; r < 16; ++r) {
                        const int kg = kt + sub * 32 + (r & 3) + 8 * (r >> 2) + 4 * hi;
                        if (kg > qg) sacc[sub][r] = -1.0e30f;
                    }
                }

            // ---- row max over 64 scores: tree + one cross-half exchange ----
            float mx[16];
            #pragma unroll
            for (int r = 0; r < 16; ++r)
                mx[r] = fmaxf(fmaxf(sacc[0][r], sacc[1][r]),
                              fmaxf(sacc[2][r], sacc[3][r]));
            #pragma unroll
            for (int s2 = 8; s2 > 0; s2 >>= 1)
                #pragma unroll
                for (int r = 0; r < s2; ++r) mx[r] = fmaxf(mx[r], mx[r + s2]);
            const float tm = fmaxf(mx[0], __shfl_xor(mx[0], 32));

            // ---- rescale (exact skip when no lane has a new max) ----
            if (!__all(tm <= mrow)) {
                const float mnew = fmaxf(mrow, tm);
                const float corr = hw_exp2(mrow - mnew);
                lrow *= corr;
                #pragma unroll
                for (int r = 0; r < 16; ++r) { oacc[0][r] *= corr; oacc[1][r] *= corr; }
                mrow = mnew;
            }

            // ---- p = exp2(s - m); tree row-sum ----
            float sm[16];
            #pragma unroll
            for (int sub = 0; sub < 4; ++sub)
                #pragma unroll
                for (int r = 0; r < 16; ++r)
                    sacc[sub][r] = hw_exp2(sacc[sub][r] - mrow);
            #pragma unroll
            for (int r = 0; r < 16; ++r)
                sm[r] = (sacc[0][r] + sacc[1][r]) + (sacc[2][r] + sacc[3][r]);
            #pragma unroll
            for (int s2 = 8; s2 > 0; s2 >>= 1)
                #pragma unroll
                for (int r = 0; r < s2; ++r) sm[r] += sm[r + s2];
            lrow += sm[0] + __shfl_xor(sm[0], 32);

            // ---- per sub: pack P and O^T += V^T @ P^T (V frags scoped) ----
            #pragma unroll
            for (int sub = 0; sub < 4; ++sub) {
                u32 wpk[8];
                #pragma unroll
                for (int i = 0; i < 8; ++i)
                    wpk[i] = cvtpk_bf16(sacc[sub][2 * i], sacc[sub][2 * i + 1]);
                u32 a0 = wpk[0], b0 = wpk[2];
                u32 a1 = wpk[1], b1 = wpk[3];
                u32 a2 = wpk[4], b2 = wpk[6];
                u32 a3 = wpk[5], b3 = wpk[7];
                asm("v_permlane32_swap_b32 %0, %1" : "+v"(a0), "+v"(b0));
                asm("v_permlane32_swap_b32 %0, %1" : "+v"(a1), "+v"(b1));
                asm("v_permlane32_swap_b32 %0, %1" : "+v"(a2), "+v"(b2));
                asm("v_permlane32_swap_b32 %0, %1" : "+v"(a3), "+v"(b3));
                u32x4 pw0, pw1;
                pw0[0] = a0; pw0[1] = a1; pw0[2] = b0; pw0[3] = b1;
                pw1[0] = a2; pw1[1] = a3; pw1[2] = b2; pw1[3] = b3;
                const bf16x8 pb0 = __builtin_bit_cast(bf16x8, pw0);
                const bf16x8 pb1 = __builtin_bit_cast(bf16x8, pw1);
                __builtin_amdgcn_s_setprio(1);
                #pragma unroll
                for (int dt = 0; dt < 2; ++dt) {
                    const int rV = dt * 32 + lq;
                    const int jx = lq & 15;
                    const bf16x8 v0 = *reinterpret_cast<const bf16x8*>(
                        &Vc[rV * 128 + (((sub * 4 + 0 * 2 + hi) ^ jx) * 8)]);
                    oacc[dt] = __builtin_amdgcn_mfma_f32_32x32x16_bf16(
                        v0, pb0, oacc[dt], 0, 0, 0);
                    const bf16x8 v1 = *reinterpret_cast<const bf16x8*>(
                        &Vc[rV * 128 + (((sub * 4 + 1 * 2 + hi) ^ jx) * 8)]);
                    oacc[dt] = __builtin_amdgcn_mfma_f32_32x32x16_bf16(
                        v1, pb1, oacc[dt], 0, 0, 0);
                }
                __builtin_amdgcn_s_setprio(0);
            }
        }
        __builtin_amdgcn_s_barrier();
        cur ^= 1;
    }

    // ---- epilogue: O^T / l -> AO[q][d] (lane's own q row) ----
    const float inv = 1.f / lrow;
    ushort* aorow = AO + (size_t)(b * S_ + qg) * 1024 + h * 64;
    #pragma unroll
    for (int dt = 0; dt < 2; ++dt)
        #pragma unroll
        for (int g = 0; g < 4; ++g) {
            const int d0 = dt * 32 + g * 8 + hi * 4;
            ushort4v pk;
            #pragma unroll
            for (int j = 0; j < 4; ++j) pk[j] = f2bf(oacc[dt][g * 4 + j] * inv);
            *reinterpret_cast<ushort4v*>(&aorow[d0]) = pk;
        }
}

// ---------------------------------------------------------------------------
extern "C" void kernel_launch(void* const* d_in, const int* in_sizes, int n_in,
                              void* d_out, int out_size, void* d_ws, size_t ws_size,
                              hipStream_t stream)
{
    const float* x  = (const float*)d_in[0];
    const float* Wq = (const float*)d_in[2];
    const float* bq = (const float*)d_in[3];
    const float* Wk = (const float*)d_in[4];
    const float* bk = (const float*)d_in[5];
    const float* Wv = (const float*)d_in[6];
    const float* bv = (const float*)d_in[7];
    const float* Wo = (const float*)d_in[8];
    const float* bo = (const float*)d_in[9];
    float* out = (float*)d_out;

    const size_t tok = (size_t)B_ * S_;            // 4096
    ushort* xb    = (ushort*)d_ws;                 // 4M elems
    ushort* WtQKV = xb + tok * E_;                 // 3M
    ushort* WtO   = WtQKV + (size_t)3072 * 1024;   // 1M
    ushort* Qb    = WtO + (size_t)1024 * 1024;     // 4M
    ushort* Kb    = Qb + tok * E_;                 // 4M
    ushort* Vt    = Kb + tok * E_;                 // 4M
    ushort* AO    = Vt + tok * E_;                 // 4M

    cast_x<<<2048, 256, 0, stream>>>(x, xb);
    castT_w<<<dim3(32, 32, 4), 256, 0, stream>>>(Wq, Wk, Wv, Wo, WtQKV, WtO);

    gemm_qkv<<<dim3(24, 32), 256, 0, stream>>>(xb, WtQKV, bq, bk, bv, Qb, Kb, Vt);

    attn10<<<512, 256, 0, stream>>>(Qb, Kb, Vt, AO);

    gemm_out<<<dim3(8, 32), 256, 0, stream>>>(AO, WtO, bo, out, 1024, 1024);
}